// Round 5
// baseline (514.851 us; speedup 1.0000x reference)
//
#include <hip/hip_runtime.h>
#include <math.h>

namespace {
constexpr int   kB       = 8192;
constexpr int   kBlock   = 256;
constexpr int   kWaves   = kBlock / 64;        // 4 waves / block
constexpr int   kGrid    = kB / kWaves;        // 2048 blocks, ONE row per wave
constexpr int   kCF4     = 8;                  // float4 per lane per chunk
constexpr int   kChunkE  = 64 * 4 * kCF4;      // 2048 elements per chunk
constexpr int   kNChunk  = kB / kChunkE;       // 4 chunks per row
constexpr float kMargin   = 0.1f;
constexpr float kThresh   = 0.5f;
constexpr float kScalePos = 2.0f;
constexpr float kScaleNeg = 40.0f;
constexpr float kEps      = 1e-5f;
}

// R5: barrier-free (one row per wave, shfl-only reductions) like R4, but the
// row is STREAMED in 4 double-buffered chunks instead of held in registers.
// R4 failure mode: 32 resident float4 = 128 VGPRs > the 128-reg allocation ->
// 33 MB of scratch spill traffic (WRITE_SIZE) and 177 us. Here the live set is
// 2x8 float4 (64 VGPRs) + 4-reg bitmask + misc ~= 100. Pass 2 re-reads the row
// from cache: sim is exactly L3-sized (256 MiB) and already L3-resident (every
// round's FETCH ~= half of sim), so the second pass costs no HBM traffic.
__global__ __launch_bounds__(kBlock, 4) void ms_rows_kernel(
    const float* __restrict__ sim,
    const int*   __restrict__ labels,
    float*       __restrict__ ws)
{
  const int tid  = threadIdx.x;
  const int lane = tid & 63;
  const int row  = blockIdx.x * kWaves + (tid >> 6);

  const int ml = labels[row];                      // wave-uniform
  const float* __restrict__ srow = sim + (size_t)row * kB;
  const int base = lane * 4;                       // lane offset within a chunk

  float4 buf[2][kCF4];

  // ---- Pass 1: mask + hardest pos/neg, double-buffered chunk stream ----
  #pragma unroll
  for (int k = 0; k < kCF4; ++k)
    buf[0][k] = *reinterpret_cast<const float4*>(srow + k * 256 + base);

  unsigned int msk[kNChunk];
  float min_pos =  INFINITY;
  float max_neg = -INFINITY;

  #pragma unroll
  for (int c = 0; c < kNChunk; ++c) {
    if (c + 1 < kNChunk) {
      #pragma unroll
      for (int k = 0; k < kCF4; ++k)
        buf[(c + 1) & 1][k] = *reinterpret_cast<const float4*>(
            srow + (c + 1) * kChunkE + k * 256 + base);
    }
    unsigned int m = 0;
    #pragma unroll
    for (int k = 0; k < kCF4; ++k) {
      const int4   l4 = *reinterpret_cast<const int4*>(labels + c * kChunkE + k * 256 + base);
      const float4 v  = buf[c & 1][k];
      const float xs[4] = {v.x, v.y, v.z, v.w};
      const int   ls[4] = {l4.x, l4.y, l4.z, l4.w};
      #pragma unroll
      for (int cc = 0; cc < 4; ++cc) {
        const bool  same = (ls[cc] == ml);
        m |= (unsigned)same << (k * 4 + cc);
        const float x = xs[cc];
        min_pos = fminf(min_pos, (same && x < 1.0f - kEps) ? x : INFINITY);
        max_neg = fmaxf(max_neg, same ? -INFINITY : x);
      }
    }
    msk[c] = m;
  }

  // Wave butterfly reduce + broadcast (no vmcnt interaction, no barriers).
  #pragma unroll
  for (int off = 32; off > 0; off >>= 1) {
    min_pos = fminf(min_pos, __shfl_xor(min_pos, off, 64));
    max_neg = fmaxf(max_neg, __shfl_xor(max_neg, off, 64));
  }

  // Keep pass-2 loads from being hoisted into pass 1 (register pressure).
  __builtin_amdgcn_sched_barrier(0);

  // ---- Pass 2: re-read row (L2/L3-hot), mined exp-sums ----
  // exp args in [-60, 20]: never underflows -> ps>0 <=> any(sel_pos).
  #pragma unroll
  for (int k = 0; k < kCF4; ++k)
    buf[0][k] = *reinterpret_cast<const float4*>(srow + k * 256 + base);

  float ps = 0.0f, ns = 0.0f;
  #pragma unroll
  for (int c = 0; c < kNChunk; ++c) {
    if (c + 1 < kNChunk) {
      #pragma unroll
      for (int k = 0; k < kCF4; ++k)
        buf[(c + 1) & 1][k] = *reinterpret_cast<const float4*>(
            srow + (c + 1) * kChunkE + k * 256 + base);
    }
    const unsigned int m = msk[c];
    #pragma unroll
    for (int k = 0; k < kCF4; ++k) {
      const float4 v = buf[c & 1][k];
      const float xs[4] = {v.x, v.y, v.z, v.w};
      #pragma unroll
      for (int cc = 0; cc < 4; ++cc) {
        const bool  same = (m >> (k * 4 + cc)) & 1u;
        const float x = xs[cc];
        const float a = same ? -kScalePos : kScaleNeg;
        const float e = __expf(a * (x - kThresh));
        ps += (same && x < 1.0f - kEps && x - kMargin < max_neg) ? e : 0.0f;
        ns += (!same && x + kMargin > min_pos) ? e : 0.0f;
      }
    }
  }

  #pragma unroll
  for (int off = 32; off > 0; off >>= 1) {
    ps += __shfl_xor(ps, off, 64);
    ns += __shfl_xor(ns, off, 64);
  }

  if (lane == 0) {
    float loss = 0.0f;
    if (ps > 0.0f && ns > 0.0f) {
      loss = log1pf(ps) * (1.0f / kScalePos)
           + log1pf(ns) * (1.0f / kScaleNeg);
    }
    ws[row] = loss;                               // no atomics
  }
}

// Sum the 8192 per-row losses, scale, write the scalar.
__global__ __launch_bounds__(256) void ms_reduce_kernel(
    const float* __restrict__ ws, float* __restrict__ out)
{
  const int tid = threadIdx.x;
  float s = 0.0f;
  #pragma unroll
  for (int i = tid; i < kB; i += 256) s += ws[i];
  #pragma unroll
  for (int off = 32; off > 0; off >>= 1) s += __shfl_xor(s, off, 64);
  __shared__ float sm[4];
  if ((tid & 63) == 0) sm[tid >> 6] = s;
  __syncthreads();
  if (tid == 0)
    out[0] = (sm[0] + sm[1] + sm[2] + sm[3]) * (1.0f / (float)kB);
}

extern "C" void kernel_launch(void* const* d_in, const int* in_sizes, int n_in,
                              void* d_out, int out_size, void* d_ws, size_t ws_size,
                              hipStream_t stream) {
  const float* sim    = (const float*)d_in[0];
  const int*   labels = (const int*)d_in[1];
  float*       ws     = (float*)d_ws;              // 8192 floats, fully rewritten
  float*       out    = (float*)d_out;             // written by reduce kernel

  ms_rows_kernel<<<dim3(kGrid), dim3(kBlock), 0, stream>>>(sim, labels, ws);
  ms_reduce_kernel<<<dim3(1), dim3(256), 0, stream>>>(ws, out);
}

// Round 6
// 377.159 us; speedup vs baseline: 1.3651x; 1.3651x over previous
//
#include <hip/hip_runtime.h>
#include <math.h>

namespace {
constexpr int   kB       = 8192;
constexpr int   kBlock   = 256;
constexpr int   kWaves   = kBlock / 64;        // 4 waves / block
constexpr int   kGrid    = kB / kWaves;        // 2048 blocks, ONE row per wave
constexpr int   kCF4     = 8;                  // float4 per lane per chunk
constexpr int   kChunkE  = 64 * 4 * kCF4;      // 2048 elements per chunk
constexpr int   kNChunk  = kB / kChunkE;       // 4 chunks per row
constexpr float kMargin   = 0.1f;
constexpr float kThresh   = 0.5f;
constexpr float kScalePos = 2.0f;
constexpr float kScaleNeg = 40.0f;
constexpr float kEps      = 1e-5f;
}

// R6: barrier-free row-per-wave (R5 structure) with the live set shrunk to
// fit the 64-VGPR allocation the compiler actually chooses.
// R5 failure mode: allocator picked 64 regs for an ~85-reg live set
// (buf[2][8] + 128-bit mask) -> 260 MiB spill WRITE traffic, 255 us. The
// pass-2 global re-read itself was ~92% cache-served (FETCH decomposition),
// so keep the re-read, drop the double-buffer and the persistent mask:
//  - single 8xfloat4 chunk buffer (32 regs)
//  - `same` recomputed in pass 2 from L1-resident labels (1 cmp/elem)
//  - outer chunk loops forced rolled (#pragma unroll 1) so the scheduler
//    cannot hoist next-chunk loads and recreate the pressure.
// Live set ~50 regs -> no spill -> 8 waves/SIMD; latency hidden by TLP from
// 32 independent, freely-drifting waves per CU. Zero __syncthreads.
__global__ __launch_bounds__(kBlock, 4) void ms_rows_kernel(
    const float* __restrict__ sim,
    const int*   __restrict__ labels,
    float*       __restrict__ ws)
{
  const int tid  = threadIdx.x;
  const int lane = tid & 63;
  const int row  = blockIdx.x * kWaves + (tid >> 6);

  const int ml = labels[row];                      // wave-uniform
  const float* __restrict__ srow = sim + (size_t)row * kB;
  const int base = lane * 4;

  // ---- Pass 1: hardest positive / hardest negative ----
  float min_pos =  INFINITY;
  float max_neg = -INFINITY;
  #pragma unroll 1
  for (int c = 0; c < kNChunk; ++c) {
    const float* __restrict__ p  = srow   + c * kChunkE + base;
    const int*   __restrict__ lp = labels + c * kChunkE + base;
    float4 v[kCF4];
    #pragma unroll
    for (int k = 0; k < kCF4; ++k)
      v[k] = *reinterpret_cast<const float4*>(p + k * 256);
    #pragma unroll
    for (int k = 0; k < kCF4; ++k) {
      const int4  l4 = *reinterpret_cast<const int4*>(lp + k * 256);
      const float xs[4] = {v[k].x, v[k].y, v[k].z, v[k].w};
      const int   ls[4] = {l4.x, l4.y, l4.z, l4.w};
      #pragma unroll
      for (int cc = 0; cc < 4; ++cc) {
        const bool  same = (ls[cc] == ml);
        const float x = xs[cc];
        min_pos = fminf(min_pos, (same && x < 1.0f - kEps) ? x : INFINITY);
        max_neg = fmaxf(max_neg, same ? -INFINITY : x);
      }
    }
  }

  // Wave butterfly reduce + broadcast (shfl only — no vmcnt, no barrier).
  #pragma unroll
  for (int off = 32; off > 0; off >>= 1) {
    min_pos = fminf(min_pos, __shfl_xor(min_pos, off, 64));
    max_neg = fmaxf(max_neg, __shfl_xor(max_neg, off, 64));
  }

  // ---- Pass 2: re-read row (cache-hot), mined exp-sums ----
  // exp args in [-60, 20]: never underflows -> ps>0 <=> any(sel_pos).
  float ps = 0.0f, ns = 0.0f;
  #pragma unroll 1
  for (int c = 0; c < kNChunk; ++c) {
    const float* __restrict__ p  = srow   + c * kChunkE + base;
    const int*   __restrict__ lp = labels + c * kChunkE + base;
    float4 v[kCF4];
    #pragma unroll
    for (int k = 0; k < kCF4; ++k)
      v[k] = *reinterpret_cast<const float4*>(p + k * 256);
    #pragma unroll
    for (int k = 0; k < kCF4; ++k) {
      const int4  l4 = *reinterpret_cast<const int4*>(lp + k * 256);
      const float xs[4] = {v[k].x, v[k].y, v[k].z, v[k].w};
      const int   ls[4] = {l4.x, l4.y, l4.z, l4.w};
      #pragma unroll
      for (int cc = 0; cc < 4; ++cc) {
        const bool  same = (ls[cc] == ml);
        const float x = xs[cc];
        const float a = same ? -kScalePos : kScaleNeg;
        const float e = __expf(a * (x - kThresh));
        ps += (same && x < 1.0f - kEps && x - kMargin < max_neg) ? e : 0.0f;
        ns += (!same && x + kMargin > min_pos) ? e : 0.0f;
      }
    }
  }

  #pragma unroll
  for (int off = 32; off > 0; off >>= 1) {
    ps += __shfl_xor(ps, off, 64);
    ns += __shfl_xor(ns, off, 64);
  }

  if (lane == 0) {
    float loss = 0.0f;
    if (ps > 0.0f && ns > 0.0f) {
      loss = log1pf(ps) * (1.0f / kScalePos)
           + log1pf(ns) * (1.0f / kScaleNeg);
    }
    ws[row] = loss;                               // no atomics
  }
}

// Sum the 8192 per-row losses, scale, write the scalar.
__global__ __launch_bounds__(256) void ms_reduce_kernel(
    const float* __restrict__ ws, float* __restrict__ out)
{
  const int tid = threadIdx.x;
  float s = 0.0f;
  #pragma unroll
  for (int i = tid; i < kB; i += 256) s += ws[i];
  #pragma unroll
  for (int off = 32; off > 0; off >>= 1) s += __shfl_xor(s, off, 64);
  __shared__ float sm[4];
  if ((tid & 63) == 0) sm[tid >> 6] = s;
  __syncthreads();
  if (tid == 0)
    out[0] = (sm[0] + sm[1] + sm[2] + sm[3]) * (1.0f / (float)kB);
}

extern "C" void kernel_launch(void* const* d_in, const int* in_sizes, int n_in,
                              void* d_out, int out_size, void* d_ws, size_t ws_size,
                              hipStream_t stream) {
  const float* sim    = (const float*)d_in[0];
  const int*   labels = (const int*)d_in[1];
  float*       ws     = (float*)d_ws;              // 8192 floats, fully rewritten
  float*       out    = (float*)d_out;             // written by reduce kernel

  ms_rows_kernel<<<dim3(kGrid), dim3(kBlock), 0, stream>>>(sim, labels, ws);
  ms_reduce_kernel<<<dim3(1), dim3(256), 0, stream>>>(ws, out);
}